// Round 1
// baseline (1387.064 us; speedup 1.0000x reference)
//
#include <hip/hip_runtime.h>
#include <hip/hip_bf16.h>

#define BATCH 4
#define SEQ   4096
#define EMB   1024
#define PDIM  128

using short8   = __attribute__((ext_vector_type(8))) short;
using ushort8  = __attribute__((ext_vector_type(8))) unsigned short;
using ushort4v = __attribute__((ext_vector_type(4))) unsigned short;
using float4v  = __attribute__((ext_vector_type(4))) float;

__device__ __forceinline__ unsigned short f2bf(float f) {
  union { float f; unsigned int u; } x; x.f = f;
  unsigned int r = x.u + 0x7fffu + ((x.u >> 16) & 1u);   // round-to-nearest-even
  return (unsigned short)(r >> 16);
}

// ---------- cast fp32 -> bf16, row-major ----------
__global__ void cast_bf16_kernel(const float* __restrict__ src,
                                 unsigned short* __restrict__ dst, int n4) {
  int i = blockIdx.x * blockDim.x + threadIdx.x;
  if (i >= n4) return;
  float4v v = ((const float4v*)src)[i];
  ushort4v o;
  o[0] = f2bf(v[0]); o[1] = f2bf(v[1]); o[2] = f2bf(v[2]); o[3] = f2bf(v[3]);
  ((ushort4v*)dst)[i] = o;
}

// ---------- transpose + cast: src (R x C) fp32 -> dst (C x R) bf16, batched by z ----------
__global__ void transpose_cast_kernel(const float* __restrict__ src,
                                      unsigned short* __restrict__ dst, int R, int C) {
  __shared__ float tile[32][33];
  const float* s = src + (size_t)blockIdx.z * R * C;
  unsigned short* d = dst + (size_t)blockIdx.z * R * C;
  int c0 = blockIdx.x * 32, r0 = blockIdx.y * 32;
#pragma unroll
  for (int i = 0; i < 32; i += 8)
    tile[threadIdx.y + i][threadIdx.x] =
        s[(size_t)(r0 + threadIdx.y + i) * C + c0 + threadIdx.x];
  __syncthreads();
#pragma unroll
  for (int i = 0; i < 32; i += 8)
    d[(size_t)(c0 + threadIdx.y + i) * R + r0 + threadIdx.x] =
        f2bf(tile[threadIdx.x][threadIdx.y + i]);
}

// ---------- GEMM: C = (A @ Bt^T + bias) * scale ----------
// A: (M,K) bf16 row-major. Bt: (N,K) bf16 row-major. 128x128 tile, 4 waves x (64x64).
__global__ __launch_bounds__(256, 2) void gemm_bt_kernel(
    const unsigned short* __restrict__ A, const unsigned short* __restrict__ Bt,
    const float* __restrict__ bias, float* __restrict__ Cf,
    unsigned short* __restrict__ Cb, int M, int N, int K, float scale) {
  // 56-ushort row stride: 112B (16B-aligned rows, 28-dword stride -> 2-way bank aliasing only)
  __shared__ __attribute__((aligned(16))) unsigned short As[128][56];
  __shared__ __attribute__((aligned(16))) unsigned short Bs[128][56];
  const int tid = threadIdx.x;
  const int wave = tid >> 6, lane = tid & 63;
  const int quad = lane >> 4, l16 = lane & 15;
  const int m0 = blockIdx.x * 128, n0 = blockIdx.y * 128;
  const int mq = (wave >> 1) * 64, nq = (wave & 1) * 64;

  float4v z = {0.f, 0.f, 0.f, 0.f};
  float4v acc[4][4];
#pragma unroll
  for (int i = 0; i < 4; i++)
#pragma unroll
    for (int j = 0; j < 4; j++) acc[i][j] = z;

  for (int k0 = 0; k0 < K; k0 += 32) {
#pragma unroll
    for (int i = 0; i < 2; i++) {
      int c = tid + i * 256;
      int row = c >> 2, off = (c & 3) * 8;
      *(uint4*)(&As[row][off]) = *(const uint4*)(A + (size_t)(m0 + row) * K + k0 + off);
      *(uint4*)(&Bs[row][off]) = *(const uint4*)(Bt + (size_t)(n0 + row) * K + k0 + off);
    }
    __syncthreads();
    short8 af[4], bf[4];
#pragma unroll
    for (int t = 0; t < 4; t++) {
      af[t] = *(const short8*)(&As[mq + t * 16 + l16][quad * 8]);
      bf[t] = *(const short8*)(&Bs[nq + t * 16 + l16][quad * 8]);
    }
#pragma unroll
    for (int mt = 0; mt < 4; mt++)
#pragma unroll
      for (int nt = 0; nt < 4; nt++)
        acc[mt][nt] = __builtin_amdgcn_mfma_f32_16x16x32_bf16(af[mt], bf[nt], acc[mt][nt], 0, 0, 0);
    __syncthreads();
  }

#pragma unroll
  for (int mt = 0; mt < 4; mt++)
#pragma unroll
    for (int nt = 0; nt < 4; nt++) {
      int gn = n0 + nq + nt * 16 + l16;
      float bv = bias[gn];
#pragma unroll
      for (int r = 0; r < 4; r++) {
        int gm = m0 + mq + mt * 16 + quad * 4 + r;
        float v = (acc[mt][nt][r] + bv) * scale;
        if (Cb) Cb[(size_t)gm * N + gn] = f2bf(v);
        else    Cf[(size_t)gm * N + gn] = v;
      }
    }
}

// ---------- flash attention: ctx = softmax(q k^T) @ x  (per batch) ----------
// q pre-scaled by 1/sqrt(128). Q-tile=32 rows, K-tile=64 keys, 4 waves each owning 256 dims.
__global__ __launch_bounds__(256, 2) void attn_kernel(
    const unsigned short* __restrict__ qg,  // (B*S, 128) bf16
    const unsigned short* __restrict__ kg,  // (B*S, 128) bf16
    const unsigned short* __restrict__ xT,  // (B, 1024, S) bf16
    unsigned short* __restrict__ ctx) {     // (B*S, 1024) bf16
  __shared__ __attribute__((aligned(16))) unsigned short q_s[32][136];
  __shared__ __attribute__((aligned(16))) unsigned short k_s[64][136];
  __shared__ __attribute__((aligned(16))) float          s_s[32][68];
  __shared__ __attribute__((aligned(16))) unsigned short p_s[32][72];
  __shared__ float red[32][8];
  __shared__ float mrow[32], lrow[32], arow[32];

  const int tid = threadIdx.x;
  const int w = tid >> 6, lane = tid & 63;
  const int quad = lane >> 4, l16 = lane & 15;
  const int q0 = blockIdx.x * 32;
  const int b = blockIdx.y;
  const int srow = tid & 31, schunk = tid >> 5;

  // stage Q tile (32 x 128 bf16)
#pragma unroll
  for (int i = 0; i < 2; i++) {
    int c = tid + i * 256;
    int row = c >> 4, off = (c & 15) * 8;
    *(uint4*)(&q_s[row][off]) =
        *(const uint4*)(qg + (size_t)(b * SEQ + q0 + row) * PDIM + off);
  }
  if (tid < 32) { mrow[tid] = -1e30f; lrow[tid] = 0.f; }
  __syncthreads();

  short8 aq[2][4];
#pragma unroll
  for (int mt = 0; mt < 2; mt++)
#pragma unroll
    for (int ks = 0; ks < 4; ks++)
      aq[mt][ks] = *(const short8*)(&q_s[mt * 16 + l16][ks * 32 + quad * 8]);

  float4v z = {0.f, 0.f, 0.f, 0.f};
  float4v acc[2][16];
#pragma unroll
  for (int mt = 0; mt < 2; mt++)
#pragma unroll
    for (int nt = 0; nt < 16; nt++) acc[mt][nt] = z;

  const unsigned short* xTb = xT + (size_t)b * EMB * SEQ;

  for (int kb = 0; kb < SEQ; kb += 64) {
    // stage K tile (64 x 128)
#pragma unroll
    for (int i = 0; i < 4; i++) {
      int c = tid + i * 256;
      int row = c >> 4, off = (c & 15) * 8;
      *(uint4*)(&k_s[row][off]) =
          *(const uint4*)(kg + (size_t)(b * SEQ + kb + row) * PDIM + off);
    }
    __syncthreads();

    // scores: wave w owns keys [w*16, w*16+16), both 16-row m-tiles
    float4v sc[2] = {z, z};
#pragma unroll
    for (int ks = 0; ks < 4; ks++) {
      short8 bk = *(const short8*)(&k_s[w * 16 + l16][ks * 32 + quad * 8]);
#pragma unroll
      for (int mt = 0; mt < 2; mt++)
        sc[mt] = __builtin_amdgcn_mfma_f32_16x16x32_bf16(aq[mt][ks], bk, sc[mt], 0, 0, 0);
    }
#pragma unroll
    for (int mt = 0; mt < 2; mt++)
#pragma unroll
      for (int r = 0; r < 4; r++)
        s_s[mt * 16 + quad * 4 + r][w * 16 + l16] = sc[mt][r];
    __syncthreads();

    // softmax: thread -> (row = tid&31, 8-key chunk = tid>>5)
    float4v v0 = *(const float4v*)(&s_s[srow][schunk * 8]);
    float4v v1 = *(const float4v*)(&s_s[srow][schunk * 8 + 4]);
    float cmax = fmaxf(fmaxf(fmaxf(v0[0], v0[1]), fmaxf(v0[2], v0[3])),
                       fmaxf(fmaxf(v1[0], v1[1]), fmaxf(v1[2], v1[3])));
    red[srow][schunk] = cmax;
    __syncthreads();
    if (tid < 32) {
      float m_old = mrow[tid];
      float mc = red[tid][0];
#pragma unroll
      for (int c = 1; c < 8; c++) mc = fmaxf(mc, red[tid][c]);
      float m_new = fmaxf(m_old, mc);
      float alpha = __expf(m_old - m_new);
      mrow[tid] = m_new; arow[tid] = alpha; lrow[tid] *= alpha;
    }
    __syncthreads();
    float m_new = mrow[srow];
    float p0 = __expf(v0[0] - m_new), p1 = __expf(v0[1] - m_new);
    float p2 = __expf(v0[2] - m_new), p3 = __expf(v0[3] - m_new);
    float p4 = __expf(v1[0] - m_new), p5 = __expf(v1[1] - m_new);
    float p6 = __expf(v1[2] - m_new), p7 = __expf(v1[3] - m_new);
    float psum = ((p0 + p1) + (p2 + p3)) + ((p4 + p5) + (p6 + p7));
    ushort8 pu;
    pu[0] = f2bf(p0); pu[1] = f2bf(p1); pu[2] = f2bf(p2); pu[3] = f2bf(p3);
    pu[4] = f2bf(p4); pu[5] = f2bf(p5); pu[6] = f2bf(p6); pu[7] = f2bf(p7);
    *(ushort8*)(&p_s[srow][schunk * 8]) = pu;
    red[srow][schunk] = psum;
    __syncthreads();
    if (tid < 32) {
      float s = red[tid][0];
#pragma unroll
      for (int c = 1; c < 8; c++) s += red[tid][c];
      lrow[tid] += s;  // already rescaled by alpha above
    }

    // rescale accumulator by alpha (per q-row)
    float al[2][4];
#pragma unroll
    for (int mt = 0; mt < 2; mt++)
#pragma unroll
      for (int r = 0; r < 4; r++) al[mt][r] = arow[mt * 16 + quad * 4 + r];
#pragma unroll
    for (int mt = 0; mt < 2; mt++)
#pragma unroll
      for (int nt = 0; nt < 16; nt++)
#pragma unroll
        for (int r = 0; r < 4; r++) acc[mt][nt][r] *= al[mt][r];

    // PV: P (32x64, LDS) x V (64 x 1024, direct from xT global). Wave owns dims [w*256, w*256+256).
#pragma unroll
    for (int ks2 = 0; ks2 < 2; ks2++) {
      short8 pf[2];
#pragma unroll
      for (int mt = 0; mt < 2; mt++)
        pf[mt] = *(const short8*)(&p_s[mt * 16 + l16][ks2 * 32 + quad * 8]);
      const int kcol = kb + ks2 * 32 + quad * 8;
#pragma unroll
      for (int nt = 0; nt < 16; nt++) {
        int n = w * 256 + nt * 16 + l16;
        short8 vf = *(const short8*)(xTb + (size_t)n * SEQ + kcol);
#pragma unroll
        for (int mt = 0; mt < 2; mt++)
          acc[mt][nt] = __builtin_amdgcn_mfma_f32_16x16x32_bf16(pf[mt], vf, acc[mt][nt], 0, 0, 0);
      }
    }
  }
  __syncthreads();

  float linv[2][4];
#pragma unroll
  for (int mt = 0; mt < 2; mt++)
#pragma unroll
    for (int r = 0; r < 4; r++) linv[mt][r] = 1.f / lrow[mt * 16 + quad * 4 + r];
#pragma unroll
  for (int mt = 0; mt < 2; mt++)
#pragma unroll
    for (int nt = 0; nt < 16; nt++) {
      int gn = w * 256 + nt * 16 + l16;
#pragma unroll
      for (int r = 0; r < 4; r++) {
        int gm = b * SEQ + q0 + mt * 16 + quad * 4 + r;
        ctx[(size_t)gm * EMB + gn] = f2bf(acc[mt][nt][r] * linv[mt][r]);
      }
    }
}

extern "C" void kernel_launch(void* const* d_in, const int* in_sizes, int n_in,
                              void* d_out, int out_size, void* d_ws, size_t ws_size,
                              hipStream_t stream) {
  const float* x   = (const float*)d_in[0];
  const float* Wq  = (const float*)d_in[1];
  const float* bq  = (const float*)d_in[2];
  const float* Wk  = (const float*)d_in[3];
  const float* bk  = (const float*)d_in[4];
  const float* Wov = (const float*)d_in[5];
  const float* bov = (const float*)d_in[6];
  float* out = (float*)d_out;

  char* ws = (char*)d_ws;
  size_t off = 0;
  auto alloc = [&](size_t bytes) {
    char* p = ws + off;
    off += (bytes + 255) & ~(size_t)255;
    return p;
  };
  unsigned short* x_bf = (unsigned short*)alloc((size_t)BATCH * SEQ * EMB * 2);
  unsigned short* xT   = (unsigned short*)alloc((size_t)BATCH * SEQ * EMB * 2);
  unsigned short* WqT  = (unsigned short*)alloc((size_t)EMB * PDIM * 2);
  unsigned short* WkT  = (unsigned short*)alloc((size_t)EMB * PDIM * 2);
  unsigned short* WovT = (unsigned short*)alloc((size_t)EMB * EMB * 2);
  unsigned short* qb   = (unsigned short*)alloc((size_t)BATCH * SEQ * PDIM * 2);
  unsigned short* kbuf = (unsigned short*)alloc((size_t)BATCH * SEQ * PDIM * 2);
  unsigned short* ctx  = (unsigned short*)alloc((size_t)BATCH * SEQ * EMB * 2);

  const int M = BATCH * SEQ;  // 16384

  cast_bf16_kernel<<<(M * EMB / 4 + 255) / 256, 256, 0, stream>>>(x, x_bf, M * EMB / 4);
  transpose_cast_kernel<<<dim3(EMB / 32, SEQ / 32, BATCH), dim3(32, 8), 0, stream>>>(x, xT, SEQ, EMB);
  transpose_cast_kernel<<<dim3(PDIM / 32, EMB / 32, 1), dim3(32, 8), 0, stream>>>(Wq, WqT, EMB, PDIM);
  transpose_cast_kernel<<<dim3(PDIM / 32, EMB / 32, 1), dim3(32, 8), 0, stream>>>(Wk, WkT, EMB, PDIM);
  transpose_cast_kernel<<<dim3(EMB / 32, EMB / 32, 1), dim3(32, 8), 0, stream>>>(Wov, WovT, EMB, EMB);

  const float qscale = 0.08838834764831845f;  // 1/sqrt(128), folded into q
  gemm_bt_kernel<<<dim3(M / 128, PDIM / 128), 256, 0, stream>>>(x_bf, WqT, bq, nullptr, qb, M, PDIM, EMB, qscale);
  gemm_bt_kernel<<<dim3(M / 128, PDIM / 128), 256, 0, stream>>>(x_bf, WkT, bk, nullptr, kbuf, M, PDIM, EMB, 1.0f);

  attn_kernel<<<dim3(SEQ / 32, BATCH), 256, 0, stream>>>(qb, kbuf, xT, ctx);

  gemm_bt_kernel<<<dim3(M / 128, EMB / 128), 256, 0, stream>>>(ctx, WovT, bov, out, nullptr, M, EMB, EMB, 1.0f);
}

// Round 2
// 478.313 us; speedup vs baseline: 2.8999x; 2.8999x over previous
//
#include <hip/hip_runtime.h>
#include <hip/hip_bf16.h>

#define BATCH 4
#define SEQ   4096
#define EMB   1024
#define PDIM  128

using short8   = __attribute__((ext_vector_type(8))) short;
using ushort8  = __attribute__((ext_vector_type(8))) unsigned short;
using ushort4v = __attribute__((ext_vector_type(4))) unsigned short;
using float4v  = __attribute__((ext_vector_type(4))) float;

__device__ __forceinline__ unsigned short f2bf(float f) {
  union { float f; unsigned int u; } x; x.f = f;
  unsigned int r = x.u + 0x7fffu + ((x.u >> 16) & 1u);   // round-to-nearest-even
  return (unsigned short)(r >> 16);
}
__device__ __forceinline__ float bf2f(unsigned short u) {
  union { unsigned int u; float f; } x; x.u = ((unsigned int)u) << 16;
  return x.f;
}

// async global->LDS, 16B per lane; LDS dest = wave-uniform base + lane*16
__device__ __forceinline__ void gld_lds16(const unsigned short* g, unsigned short* l) {
  __builtin_amdgcn_global_load_lds(
      (__attribute__((address_space(1))) void*)(g),
      (__attribute__((address_space(3))) void*)(l), 16, 0, 0);
}

// ---------- cast fp32 -> bf16, row-major ----------
__global__ void cast_bf16_kernel(const float* __restrict__ src,
                                 unsigned short* __restrict__ dst, int n4) {
  int i = blockIdx.x * blockDim.x + threadIdx.x;
  if (i >= n4) return;
  float4v v = ((const float4v*)src)[i];
  ushort4v o;
  o[0] = f2bf(v[0]); o[1] = f2bf(v[1]); o[2] = f2bf(v[2]); o[3] = f2bf(v[3]);
  ((ushort4v*)dst)[i] = o;
}

// ---------- transpose + cast: src (R x C) fp32 -> dst (C x R) bf16, batched by z ----------
__global__ void transpose_cast_kernel(const float* __restrict__ src,
                                      unsigned short* __restrict__ dst, int R, int C) {
  __shared__ float tile[32][33];
  const float* s = src + (size_t)blockIdx.z * R * C;
  unsigned short* d = dst + (size_t)blockIdx.z * R * C;
  int c0 = blockIdx.x * 32, r0 = blockIdx.y * 32;
#pragma unroll
  for (int i = 0; i < 32; i += 8)
    tile[threadIdx.y + i][threadIdx.x] =
        s[(size_t)(r0 + threadIdx.y + i) * C + c0 + threadIdx.x];
  __syncthreads();
#pragma unroll
  for (int i = 0; i < 32; i += 8)
    d[(size_t)(c0 + threadIdx.y + i) * R + r0 + threadIdx.x] =
        f2bf(tile[threadIdx.x][threadIdx.y + i]);
}

__global__ void concat_bias_kernel(const float* __restrict__ a,
                                   const float* __restrict__ b,
                                   float* __restrict__ o) {
  int i = threadIdx.x;
  o[i] = (i < PDIM) ? a[i] : b[i - PDIM];
}

// ---------- m97-style GEMM: C = f(A @ Bt^T) ----------
// A: (M,K) bf16 row-major (lda). Bt: (N,K) bf16 row-major (ldb).
// 128x128 tile, BK=32, 4 waves x (64x64), global_load_lds width=16.
// mode: 0 = fp32 acc+bias  | 1 = bf16 exp(acc*scale) | 2 = bf16 acc*rowscale[row] | 3 = bf16 acc+bias
__global__ __launch_bounds__(256, 2) void gemm_kernel(
    const unsigned short* __restrict__ A, int lda, size_t saz,
    const unsigned short* __restrict__ Bt, int ldb, size_t sbz,
    void* __restrict__ Cv, int ldc, size_t scz,
    int K, const float* __restrict__ bias,
    const float* __restrict__ rowscale, int srz,
    float scale, int mode) {
  __shared__ __attribute__((aligned(16))) unsigned short As[128 * 32];
  __shared__ __attribute__((aligned(16))) unsigned short Bs[128 * 32];
  const int tid = threadIdx.x;
  const int wave = tid >> 6, lane = tid & 63;
  const int quad = lane >> 4, l16 = lane & 15;
  const int m0 = blockIdx.x * 128, n0 = blockIdx.y * 128;
  const int z = blockIdx.z;
  const int mq = (wave >> 1) * 64, nq = (wave & 1) * 64;

  A  += (size_t)z * saz;
  Bt += (size_t)z * sbz;

  // staging: 8 chunks of 16 rows x 32 cols per matrix; wave w stages chunks 2w, 2w+1
  const int c0 = wave * 2, c1 = wave * 2 + 1;
  const int r0 = c0 * 16 + (lane >> 2), r1 = c1 * 16 + (lane >> 2);
  const int koff = (lane & 3) * 8;
  const unsigned short* Ag0 = A + (size_t)(m0 + r0) * lda + koff;
  const unsigned short* Ag1 = A + (size_t)(m0 + r1) * lda + koff;
  const unsigned short* Bg0 = Bt + (size_t)(n0 + r0) * ldb + koff;
  const unsigned short* Bg1 = Bt + (size_t)(n0 + r1) * ldb + koff;
  unsigned short* Al0 = As + c0 * 16 * 32;  // wave-uniform LDS bases
  unsigned short* Al1 = As + c1 * 16 * 32;
  unsigned short* Bl0 = Bs + c0 * 16 * 32;
  unsigned short* Bl1 = Bs + c1 * 16 * 32;

  float4v zf = {0.f, 0.f, 0.f, 0.f};
  float4v acc[4][4];
#pragma unroll
  for (int i = 0; i < 4; i++)
#pragma unroll
    for (int j = 0; j < 4; j++) acc[i][j] = zf;

  for (int k0 = 0; k0 < K; k0 += 32) {
    if (k0) __syncthreads();
    gld_lds16(Ag0 + k0, Al0);
    gld_lds16(Ag1 + k0, Al1);
    gld_lds16(Bg0 + k0, Bl0);
    gld_lds16(Bg1 + k0, Bl1);
    __syncthreads();  // compiler emits s_waitcnt vmcnt(0) before s_barrier

    short8 af[4], bf[4];
#pragma unroll
    for (int t = 0; t < 4; t++) {
      af[t] = *(const short8*)(As + (mq + t * 16 + l16) * 32 + quad * 8);
      bf[t] = *(const short8*)(Bs + (nq + t * 16 + l16) * 32 + quad * 8);
    }
#pragma unroll
    for (int mt = 0; mt < 4; mt++)
#pragma unroll
      for (int nt = 0; nt < 4; nt++)
        acc[mt][nt] = __builtin_amdgcn_mfma_f32_16x16x32_bf16(af[mt], bf[nt], acc[mt][nt], 0, 0, 0);
  }

  float* Cf = (float*)Cv + (size_t)z * scz;
  unsigned short* Cb = (unsigned short*)Cv + (size_t)z * scz;
  const float* rs = rowscale ? rowscale + (size_t)z * srz : nullptr;

#pragma unroll
  for (int mt = 0; mt < 4; mt++)
#pragma unroll
    for (int nt = 0; nt < 4; nt++) {
      int gn = n0 + nq + nt * 16 + l16;
      float bv = (mode == 0 || mode == 3) ? bias[gn] : 0.f;
#pragma unroll
      for (int r = 0; r < 4; r++) {
        int gm = m0 + mq + mt * 16 + quad * 4 + r;
        float v = acc[mt][nt][r];
        if (mode == 0)      Cf[(size_t)gm * ldc + gn] = v + bv;
        else if (mode == 1) Cb[(size_t)gm * ldc + gn] = f2bf(__expf(v * scale));
        else if (mode == 2) Cb[(size_t)gm * ldc + gn] = f2bf(v * rs[gm]);
        else                Cb[(size_t)gm * ldc + gn] = f2bf(v + bv);
      }
    }
}

// ---------- row-sum of P (bf16, N cols) -> 1/sum (fp32) ----------
__global__ void rowsum_kernel(const unsigned short* __restrict__ P,
                              float* __restrict__ linv, int N) {
  const int row = blockIdx.x, b = blockIdx.y, tid = threadIdx.x;
  const unsigned short* p = P + (size_t)b * SEQ * SEQ + (size_t)row * N;
  float s = 0.f;
  for (int i = tid * 8; i < N; i += 256 * 8) {
    ushort8 v = *(const ushort8*)(p + i);
#pragma unroll
    for (int j = 0; j < 8; j++) s += bf2f(v[j]);
  }
#pragma unroll
  for (int o = 32; o > 0; o >>= 1) s += __shfl_down(s, o);
  __shared__ float rs[4];
  if ((tid & 63) == 0) rs[tid >> 6] = s;
  __syncthreads();
  if (tid == 0) linv[(size_t)b * SEQ + row] = 1.f / (rs[0] + rs[1] + rs[2] + rs[3]);
}

extern "C" void kernel_launch(void* const* d_in, const int* in_sizes, int n_in,
                              void* d_out, int out_size, void* d_ws, size_t ws_size,
                              hipStream_t stream) {
  const float* x   = (const float*)d_in[0];
  const float* Wq  = (const float*)d_in[1];
  const float* bq  = (const float*)d_in[2];
  const float* Wk  = (const float*)d_in[3];
  const float* bk  = (const float*)d_in[4];
  const float* Wov = (const float*)d_in[5];
  const float* bov = (const float*)d_in[6];
  float* out = (float*)d_out;

  char* ws = (char*)d_ws;
  size_t off = 0;
  auto alloc = [&](size_t bytes) {
    char* p = ws + off;
    off += (bytes + 255) & ~(size_t)255;
    return p;
  };
  const int M = BATCH * SEQ;  // 16384
  unsigned short* x_bf = (unsigned short*)alloc((size_t)M * EMB * 2);
  unsigned short* xT   = (unsigned short*)alloc((size_t)M * EMB * 2);
  unsigned short* WqkT = (unsigned short*)alloc((size_t)2 * PDIM * EMB * 2);
  unsigned short* WovT = (unsigned short*)alloc((size_t)EMB * EMB * 2);
  float*          bqk  = (float*)alloc(2 * PDIM * sizeof(float));
  unsigned short* qk   = (unsigned short*)alloc((size_t)M * 2 * PDIM * 2);
  float*          linv = (float*)alloc((size_t)M * sizeof(float));
  unsigned short* ctx  = (unsigned short*)alloc((size_t)M * EMB * 2);
  // P slots: as many 32MB batch slots as ws allows (constant per session -> graph-safe)
  const size_t pslot = (size_t)SEQ * SEQ * 2;
  unsigned short* P = (unsigned short*)(ws + off);
  size_t rem = ws_size > off ? ws_size - off : 0;
  int g = (rem >= 4 * pslot) ? 4 : (rem >= 2 * pslot) ? 2 : 1;

  // ---- prep: casts / transposes ----
  cast_bf16_kernel<<<(M * EMB / 4 + 255) / 256, 256, 0, stream>>>(x, x_bf, M * EMB / 4);
  transpose_cast_kernel<<<dim3(EMB / 32, SEQ / 32, BATCH), dim3(32, 8), 0, stream>>>(x, xT, SEQ, EMB);
  transpose_cast_kernel<<<dim3(PDIM / 32, EMB / 32, 1), dim3(32, 8), 0, stream>>>(Wq, WqkT, EMB, PDIM);
  transpose_cast_kernel<<<dim3(PDIM / 32, EMB / 32, 1), dim3(32, 8), 0, stream>>>(Wk, WqkT + (size_t)PDIM * EMB, EMB, PDIM);
  transpose_cast_kernel<<<dim3(EMB / 32, EMB / 32, 1), dim3(32, 8), 0, stream>>>(Wov, WovT, EMB, EMB);
  concat_bias_kernel<<<1, 256, 0, stream>>>(bq, bk, bqk);

  // ---- qk projection: (16384 x 1024) @ (256 x 1024)^T + bqk -> bf16 (16384 x 256) ----
  gemm_kernel<<<dim3(M / 128, 2, 1), 256, 0, stream>>>(
      x_bf, EMB, 0, WqkT, EMB, 0, qk, 2 * PDIM, 0, EMB, bqk, nullptr, 0, 1.f, 3);

  const float qscale = 0.08838834764831845f;  // 1/sqrt(128)
  for (int b0 = 0; b0 < BATCH; b0 += g) {
    int gg = (b0 + g <= BATCH) ? g : (BATCH - b0);
    // S-GEMM: P~ = exp(scale * q @ k^T), per batch slot
    gemm_kernel<<<dim3(SEQ / 128, SEQ / 128, gg), 256, 0, stream>>>(
        qk + (size_t)b0 * SEQ * 2 * PDIM, 2 * PDIM, (size_t)SEQ * 2 * PDIM,
        qk + (size_t)b0 * SEQ * 2 * PDIM + PDIM, 2 * PDIM, (size_t)SEQ * 2 * PDIM,
        P, SEQ, (size_t)SEQ * SEQ,
        PDIM, nullptr, nullptr, 0, qscale, 1);
    // rowsum -> 1/l
    rowsum_kernel<<<dim3(SEQ, gg), 256, 0, stream>>>(P, linv + (size_t)b0 * SEQ, SEQ);
    // PV: ctx = (P~ @ xT^T) * (1/l)
    gemm_kernel<<<dim3(SEQ / 128, EMB / 128, gg), 256, 0, stream>>>(
        P, SEQ, (size_t)SEQ * SEQ,
        xT + (size_t)b0 * EMB * SEQ, SEQ, (size_t)EMB * SEQ,
        ctx + (size_t)b0 * SEQ * EMB, EMB, (size_t)SEQ * EMB,
        SEQ, nullptr, linv + (size_t)b0 * SEQ, SEQ, 1.f, 2);
  }

  // ---- out projection: out = ctx @ WovT^T + bov (fp32) ----
  gemm_kernel<<<dim3(M / 128, EMB / 128, 1), 256, 0, stream>>>(
      ctx, EMB, 0, WovT, EMB, 0, out, EMB, 0, EMB, bov, nullptr, 0, 1.f, 0);
}

// Round 3
// 401.487 us; speedup vs baseline: 3.4548x; 1.1914x over previous
//
#include <hip/hip_runtime.h>
#include <hip/hip_bf16.h>

#define BATCH 4
#define SEQ   4096
#define EMB   1024
#define PDIM  128

using short8   = __attribute__((ext_vector_type(8))) short;
using ushort8  = __attribute__((ext_vector_type(8))) unsigned short;
using float4v  = __attribute__((ext_vector_type(4))) float;

__device__ __forceinline__ unsigned short f2bf(float f) {
  union { float f; unsigned int u; } x; x.f = f;
  unsigned int r = x.u + 0x7fffu + ((x.u >> 16) & 1u);   // round-to-nearest-even
  return (unsigned short)(r >> 16);
}

// async global->LDS, 16B per lane; LDS dest = wave-uniform base + lane*16
__device__ __forceinline__ void gld_lds16(const unsigned short* g, unsigned short* l) {
  __builtin_amdgcn_global_load_lds(
      (__attribute__((address_space(1))) void*)(g),
      (__attribute__((address_space(3))) void*)(l), 16, 0, 0);
}

// ---------- x prep: x (B,S,E) fp32 -> x_bf (B*S,E) bf16 row-major AND xT (B,E,S) bf16 ----------
__global__ void xprep_kernel(const float* __restrict__ src,
                             unsigned short* __restrict__ rm,
                             unsigned short* __restrict__ tp, int R, int C) {
  __shared__ float tile[32][33];
  const float* s = src + (size_t)blockIdx.z * R * C;
  unsigned short* drm = rm + (size_t)blockIdx.z * R * C;
  unsigned short* dtp = tp + (size_t)blockIdx.z * R * C;
  int c0 = blockIdx.x * 32, r0 = blockIdx.y * 32;
#pragma unroll
  for (int i = 0; i < 32; i += 8) {
    float v = s[(size_t)(r0 + threadIdx.y + i) * C + c0 + threadIdx.x];
    tile[threadIdx.y + i][threadIdx.x] = v;
    drm[(size_t)(r0 + threadIdx.y + i) * C + c0 + threadIdx.x] = f2bf(v);
  }
  __syncthreads();
#pragma unroll
  for (int i = 0; i < 32; i += 8)
    dtp[(size_t)(c0 + threadIdx.y + i) * R + r0 + threadIdx.x] =
        f2bf(tile[threadIdx.x][threadIdx.y + i]);
}

// ---------- transpose + cast: src (R x C) fp32 -> dst (C x R) bf16 ----------
__global__ void transpose_cast_kernel(const float* __restrict__ src,
                                      unsigned short* __restrict__ dst, int R, int C) {
  __shared__ float tile[32][33];
  int c0 = blockIdx.x * 32, r0 = blockIdx.y * 32;
#pragma unroll
  for (int i = 0; i < 32; i += 8)
    tile[threadIdx.y + i][threadIdx.x] =
        src[(size_t)(r0 + threadIdx.y + i) * C + c0 + threadIdx.x];
  __syncthreads();
#pragma unroll
  for (int i = 0; i < 32; i += 8)
    dst[(size_t)(c0 + threadIdx.y + i) * R + r0 + threadIdx.x] =
        f2bf(tile[threadIdx.x][threadIdx.y + i]);
}

__global__ void concat_bias_kernel(const float* __restrict__ a,
                                   const float* __restrict__ b,
                                   float* __restrict__ o) {
  int i = threadIdx.x;
  o[i] = (i < PDIM) ? a[i] : b[i - PDIM];
}

// ---------- GEMM: C = f(A @ Bt^T), 128 x NT tile, 4 waves x (64 x NT/2), BK=32 ----------
// LDS chunk-XOR swizzle: slot c in a 16-row chunk holds global k-chunk c ^ ((row>>1)&3)
// -> every 8-lane LDS phase covers all 32 banks (conflict-free reads).
// mode: 0 = fp32 acc+bias | 1 = bf16 exp(acc*scale) + atomic rowsum -> lsum
//       2 = bf16 acc / lsum[row]                    | 3 = bf16 acc+bias
template <int NT>
__global__ __launch_bounds__(256, 2) void gemm_kernel(
    const unsigned short* __restrict__ A, int lda, size_t saz,
    const unsigned short* __restrict__ Bt, int ldb, size_t sbz,
    void* __restrict__ Cv, int ldc, size_t scz,
    int K, const float* __restrict__ bias,
    float* __restrict__ lsum, int slz,
    float scale, int mode) {
  constexpr int NW = NT / 32;   // B-tiles per wave (n dir)
  constexpr int BC = NT / 64;   // B staging chunks per wave
  __shared__ __attribute__((aligned(16))) unsigned short As[128 * 32];
  __shared__ __attribute__((aligned(16))) unsigned short Bs[NT * 32];
  const int tid = threadIdx.x;
  const int wave = tid >> 6, lane = tid & 63;
  const int quad = lane >> 4, l16 = lane & 15;
  const int m0 = blockIdx.x * 128, n0 = blockIdx.y * NT;
  const int z = blockIdx.z;
  const int mq = (wave >> 1) * 64, nq = (wave & 1) * (NT / 2);

  A  += (size_t)z * saz;
  Bt += (size_t)z * sbz;

  // staging source: lane -> local row lr, swizzled global k-offset
  const int lr = lane >> 2;
  const int koff = (((lane & 3) ^ ((lane >> 3) & 3)) << 3);
  const unsigned short* Ag[2];
  unsigned short* Al[2];
#pragma unroll
  for (int j = 0; j < 2; j++) {
    int c = wave * 2 + j;
    Ag[j] = A + (size_t)(m0 + c * 16 + lr) * lda + koff;
    Al[j] = As + c * 512;
  }
  const unsigned short* Bg[BC];
  unsigned short* Bl[BC];
#pragma unroll
  for (int j = 0; j < BC; j++) {
    int c = wave * BC + j;
    Bg[j] = Bt + (size_t)(n0 + c * 16 + lr) * ldb + koff;
    Bl[j] = Bs + c * 512;
  }

  float4v zf = {0.f, 0.f, 0.f, 0.f};
  float4v acc[4][NW];
#pragma unroll
  for (int i = 0; i < 4; i++)
#pragma unroll
    for (int j = 0; j < NW; j++) acc[i][j] = zf;

  const int rsw = ((l16 >> 1) & 3);  // read-side swizzle sel for this lane's rows

  for (int k0 = 0; k0 < K; k0 += 32) {
    if (k0) __syncthreads();
#pragma unroll
    for (int j = 0; j < 2; j++) gld_lds16(Ag[j] + k0, Al[j]);
#pragma unroll
    for (int j = 0; j < BC; j++) gld_lds16(Bg[j] + k0, Bl[j]);
    __syncthreads();

    short8 af[4], bfr[NW];
#pragma unroll
    for (int t = 0; t < 4; t++)
      af[t] = *(const short8*)(As + (mq + t * 16 + l16) * 32 + ((quad ^ rsw) << 3));
#pragma unroll
    for (int t = 0; t < NW; t++)
      bfr[t] = *(const short8*)(Bs + (nq + t * 16 + l16) * 32 + ((quad ^ rsw) << 3));
#pragma unroll
    for (int mt = 0; mt < 4; mt++)
#pragma unroll
      for (int nt = 0; nt < NW; nt++)
        acc[mt][nt] = __builtin_amdgcn_mfma_f32_16x16x32_bf16(af[mt], bfr[nt], acc[mt][nt], 0, 0, 0);
  }

  float* Cf = (float*)Cv + (size_t)z * scz;
  unsigned short* Cb = (unsigned short*)Cv + (size_t)z * scz;

  if (mode == 1) {
    float rsum[4][4];
#pragma unroll
    for (int mt = 0; mt < 4; mt++)
#pragma unroll
      for (int r = 0; r < 4; r++) rsum[mt][r] = 0.f;
#pragma unroll
    for (int mt = 0; mt < 4; mt++)
#pragma unroll
      for (int nt = 0; nt < NW; nt++) {
        int gn = n0 + nq + nt * 16 + l16;
#pragma unroll
        for (int r = 0; r < 4; r++) {
          float e = __expf(acc[mt][nt][r] * scale);
          Cb[(size_t)(m0 + mq + mt * 16 + quad * 4 + r) * ldc + gn] = f2bf(e);
          rsum[mt][r] += e;
        }
      }
#pragma unroll
    for (int mt = 0; mt < 4; mt++)
#pragma unroll
      for (int r = 0; r < 4; r++) {
        float s = rsum[mt][r];
#pragma unroll
        for (int o = 1; o < 16; o <<= 1) s += __shfl_xor(s, o);
        rsum[mt][r] = s;
      }
    if (l16 == 0) {
#pragma unroll
      for (int mt = 0; mt < 4; mt++)
#pragma unroll
        for (int r = 0; r < 4; r++)
          atomicAdd(&lsum[(size_t)z * slz + m0 + mq + mt * 16 + quad * 4 + r], rsum[mt][r]);
    }
  } else if (mode == 2) {
    float linv[4][4];
#pragma unroll
    for (int mt = 0; mt < 4; mt++)
#pragma unroll
      for (int r = 0; r < 4; r++)
        linv[mt][r] = 1.f / lsum[(size_t)z * slz + m0 + mq + mt * 16 + quad * 4 + r];
#pragma unroll
    for (int mt = 0; mt < 4; mt++)
#pragma unroll
      for (int nt = 0; nt < NW; nt++) {
        int gn = n0 + nq + nt * 16 + l16;
#pragma unroll
        for (int r = 0; r < 4; r++)
          Cb[(size_t)(m0 + mq + mt * 16 + quad * 4 + r) * ldc + gn] =
              f2bf(acc[mt][nt][r] * linv[mt][r]);
      }
  } else {
#pragma unroll
    for (int mt = 0; mt < 4; mt++)
#pragma unroll
      for (int nt = 0; nt < NW; nt++) {
        int gn = n0 + nq + nt * 16 + l16;
        float bv = bias[gn];
#pragma unroll
        for (int r = 0; r < 4; r++) {
          int gm = m0 + mq + mt * 16 + quad * 4 + r;
          float v = acc[mt][nt][r] + bv;
          if (mode == 0) Cf[(size_t)gm * ldc + gn] = v;
          else           Cb[(size_t)gm * ldc + gn] = f2bf(v);
        }
      }
  }
}

extern "C" void kernel_launch(void* const* d_in, const int* in_sizes, int n_in,
                              void* d_out, int out_size, void* d_ws, size_t ws_size,
                              hipStream_t stream) {
  const float* x   = (const float*)d_in[0];
  const float* Wq  = (const float*)d_in[1];
  const float* bq  = (const float*)d_in[2];
  const float* Wk  = (const float*)d_in[3];
  const float* bk  = (const float*)d_in[4];
  const float* Wov = (const float*)d_in[5];
  const float* bov = (const float*)d_in[6];
  float* out = (float*)d_out;

  char* ws = (char*)d_ws;
  size_t off = 0;
  auto alloc = [&](size_t bytes) {
    char* p = ws + off;
    off += (bytes + 255) & ~(size_t)255;
    return p;
  };
  const int M = BATCH * SEQ;  // 16384
  unsigned short* x_bf = (unsigned short*)alloc((size_t)M * EMB * 2);
  unsigned short* xT   = (unsigned short*)alloc((size_t)M * EMB * 2);
  unsigned short* WqkT = (unsigned short*)alloc((size_t)2 * PDIM * EMB * 2);
  unsigned short* WovT = (unsigned short*)alloc((size_t)EMB * EMB * 2);
  float*          bqk  = (float*)alloc(2 * PDIM * sizeof(float));
  unsigned short* qk   = (unsigned short*)alloc((size_t)M * 2 * PDIM * 2);
  float*          linv = (float*)alloc((size_t)M * sizeof(float));
  unsigned short* ctx  = (unsigned short*)alloc((size_t)M * EMB * 2);
  const size_t pslot = (size_t)SEQ * SEQ * 2;
  unsigned short* P = (unsigned short*)(ws + off);
  size_t rem = ws_size > off ? ws_size - off : 0;
  int g = (rem >= 4 * pslot) ? 4 : (rem >= 2 * pslot) ? 2 : 1;

  // ---- prep ----
  xprep_kernel<<<dim3(EMB / 32, SEQ / 32, BATCH), dim3(32, 8), 0, stream>>>(x, x_bf, xT, SEQ, EMB);
  transpose_cast_kernel<<<dim3(PDIM / 32, EMB / 32), dim3(32, 8), 0, stream>>>(Wq, WqkT, EMB, PDIM);
  transpose_cast_kernel<<<dim3(PDIM / 32, EMB / 32), dim3(32, 8), 0, stream>>>(Wk, WqkT + (size_t)PDIM * EMB, EMB, PDIM);
  transpose_cast_kernel<<<dim3(EMB / 32, EMB / 32), dim3(32, 8), 0, stream>>>(Wov, WovT, EMB, EMB);
  concat_bias_kernel<<<1, 256, 0, stream>>>(bq, bk, bqk);
  hipMemsetAsync(linv, 0, M * sizeof(float), stream);

  // ---- qk projection: (16384 x 1024) @ (256 x 1024)^T + bqk -> bf16 ----
  gemm_kernel<128><<<dim3(M / 128, 2, 1), 256, 0, stream>>>(
      x_bf, EMB, 0, WqkT, EMB, 0, qk, 2 * PDIM, 0, EMB, bqk, nullptr, 0, 1.f, 3);

  const float qscale = 0.08838834764831845f;  // 1/sqrt(128)
  for (int b0 = 0; b0 < BATCH; b0 += g) {
    int gg = (b0 + g <= BATCH) ? g : (BATCH - b0);
    // S-GEMM: P~ = exp(scale * q @ k^T) + fused atomic rowsum
    gemm_kernel<256><<<dim3(SEQ / 128, SEQ / 256, gg), 256, 0, stream>>>(
        qk + (size_t)b0 * SEQ * 2 * PDIM, 2 * PDIM, (size_t)SEQ * 2 * PDIM,
        qk + (size_t)b0 * SEQ * 2 * PDIM + PDIM, 2 * PDIM, (size_t)SEQ * 2 * PDIM,
        P, SEQ, (size_t)SEQ * SEQ,
        PDIM, nullptr, linv + (size_t)b0 * SEQ, SEQ, qscale, 1);
    // PV: ctx = (P~ @ xT^T) / l
    gemm_kernel<256><<<dim3(SEQ / 128, EMB / 256, gg), 256, 0, stream>>>(
        P, SEQ, (size_t)SEQ * SEQ,
        xT + (size_t)b0 * EMB * SEQ, SEQ, (size_t)EMB * SEQ,
        ctx + (size_t)b0 * SEQ * EMB, EMB, (size_t)SEQ * EMB,
        SEQ, nullptr, linv + (size_t)b0 * SEQ, SEQ, 1.f, 2);
  }

  // ---- out projection: out = ctx @ WovT^T + bov (fp32) ----
  gemm_kernel<256><<<dim3(M / 128, EMB / 256, 1), 256, 0, stream>>>(
      ctx, EMB, 0, WovT, EMB, 0, out, EMB, 0, EMB, bov, nullptr, 0, 1.f, 0);
}

// Round 4
// 386.751 us; speedup vs baseline: 3.5864x; 1.0381x over previous
//
#include <hip/hip_runtime.h>
#include <hip/hip_bf16.h>

#define BATCH 4
#define SEQ   4096
#define EMB   1024
#define PDIM  128

using short8   = __attribute__((ext_vector_type(8))) short;
using ushort8  = __attribute__((ext_vector_type(8))) unsigned short;
using ushort4v = __attribute__((ext_vector_type(4))) unsigned short;
using float4v  = __attribute__((ext_vector_type(4))) float;
using float16v = __attribute__((ext_vector_type(16))) float;

__device__ __forceinline__ unsigned short f2bf(float f) {
  union { float f; unsigned int u; } x; x.f = f;
  unsigned int r = x.u + 0x7fffu + ((x.u >> 16) & 1u);   // round-to-nearest-even
  return (unsigned short)(r >> 16);
}

// async global->LDS, 16B per lane; LDS dest = wave-uniform base + lane*16
__device__ __forceinline__ void gld_lds16(const unsigned short* g, unsigned short* l) {
  __builtin_amdgcn_global_load_lds(
      (__attribute__((address_space(1))) void*)(g),
      (__attribute__((address_space(3))) void*)(l), 16, 0, 0);
}

// ---------- x prep: x (B,S,E) fp32 -> x_bf (B*S,E) bf16 AND xT (B,E,S) bf16 ----------
// 64x64 tiles; transposed writes are 16B/lane (128B segments per e-row).
__global__ void xprep_kernel(const float* __restrict__ src,
                             unsigned short* __restrict__ rm,
                             unsigned short* __restrict__ tp) {
  __shared__ float tile[64][65];  // pad 65: transposed-read phases hit 8 distinct banks
  const int tid = threadIdx.x;
  const int z = blockIdx.z;
  const float* s = src + (size_t)z * SEQ * EMB;
  unsigned short* drm = rm + (size_t)z * SEQ * EMB;
  unsigned short* dtp = tp + (size_t)z * SEQ * EMB;
  const int e0 = blockIdx.x * 64, s0 = blockIdx.y * 64;
#pragma unroll
  for (int i = 0; i < 4; i++) {
    int idx = tid + i * 256;
    int sr = idx >> 4, c4 = (idx & 15) * 4;
    float4v v = *(const float4v*)(s + (size_t)(s0 + sr) * EMB + e0 + c4);
    ushort4v o;
    o[0] = f2bf(v[0]); o[1] = f2bf(v[1]); o[2] = f2bf(v[2]); o[3] = f2bf(v[3]);
    *(ushort4v*)(drm + (size_t)(s0 + sr) * EMB + e0 + c4) = o;
    tile[sr][c4] = v[0]; tile[sr][c4 + 1] = v[1];
    tile[sr][c4 + 2] = v[2]; tile[sr][c4 + 3] = v[3];
  }
  __syncthreads();
#pragma unroll
  for (int i = 0; i < 2; i++) {
    int idx = tid + i * 256;
    int e = idx >> 3, sc = idx & 7;
    ushort8 o;
#pragma unroll
    for (int j = 0; j < 8; j++) o[j] = f2bf(tile[sc * 8 + j][e]);
    *(ushort8*)(dtp + (size_t)(e0 + e) * SEQ + s0 + sc * 8) = o;
  }
}

// ---------- weight prep: Wq/Wk/Wov transpose+cast, bqk concat, lsum zero — one launch ----------
__global__ void wprep_kernel(const float* __restrict__ Wq, const float* __restrict__ Wk,
                             const float* __restrict__ Wov,
                             unsigned short* __restrict__ WqkT, unsigned short* __restrict__ WovT,
                             const float* __restrict__ bq, const float* __restrict__ bk,
                             float* __restrict__ bqk, float* __restrict__ lsum) {
  __shared__ float t[32][33];
  const int bid = blockIdx.x, tid = threadIdx.x;
  const int tx = tid & 31, ty = tid >> 5;
  const float* src; unsigned short* dst; int C, bx, by;
  if (bid < 128)        { src = Wq;  dst = WqkT;                       C = PDIM; int b = bid;        bx = b & 3;  by = b >> 2; }
  else if (bid < 256)   { src = Wk;  dst = WqkT + (size_t)PDIM * EMB;  C = PDIM; int b = bid - 128;  bx = b & 3;  by = b >> 2; }
  else if (bid < 1280)  { src = Wov; dst = WovT;                       C = EMB;  int b = bid - 256;  bx = b & 31; by = b >> 5; }
  else if (bid == 1280) {
    if (tid < 2 * PDIM) bqk[tid] = (tid < PDIM) ? bq[tid] : bk[tid - PDIM];
    return;
  } else {  // 1281..1344: zero lsum (BATCH*SEQ floats)
    lsum[(bid - 1281) * 256 + tid] = 0.f;
    return;
  }
  const int c0 = bx * 32, r0 = by * 32;
#pragma unroll
  for (int i = 0; i < 32; i += 8)
    t[ty + i][tx] = src[(size_t)(r0 + ty + i) * C + c0 + tx];
  __syncthreads();
#pragma unroll
  for (int i = 0; i < 32; i += 8)
    dst[(size_t)(c0 + ty + i) * EMB + r0 + tx] = f2bf(t[tx][ty + i]);
}

// ---------- GEMM: C = f(A @ Bt^T), 128 x NT tile, BK=64, mfma 32x32x16 ----------
// LDS rows are 128B (8 chunks of 16B); slot s of row r holds global k-chunk s^(r&7)
// -> staging writes and b128 fragment reads are both conflict-free.
// mode: 0 = fp32 acc+bias | 1 = bf16 exp(acc*scale) + atomic rowsum -> lsum
//       2 = bf16 acc / lsum[row]                    | 3 = bf16 acc+bias
template <int NT>
__global__ __launch_bounds__(256, 2) void gemm_kernel(
    const unsigned short* __restrict__ A, int lda, size_t saz,
    const unsigned short* __restrict__ Bt, int ldb, size_t sbz,
    void* __restrict__ Cv, int ldc, size_t scz,
    int K, const float* __restrict__ bias,
    float* __restrict__ lsum, int slz,
    float scale, int mode) {
  constexpr int NTW = NT / 64;   // 32-wide n-tiles per wave
  constexpr int BC  = NT / 32;   // 8-row B staging chunks per wave
  __shared__ __attribute__((aligned(16))) unsigned short As[128 * 64];
  __shared__ __attribute__((aligned(16))) unsigned short Bs[NT * 64];
  const int tid = threadIdx.x;
  const int wave = tid >> 6, lane = tid & 63;
  const int m0 = blockIdx.x * 128, n0 = blockIdx.y * NT;
  const int z = blockIdx.z;
  const int mq = (wave >> 1) * 64, nq = (wave & 1) * (NT / 2);

  A  += (size_t)z * saz;
  Bt += (size_t)z * sbz;

  // staging: lane -> row lane>>3 of an 8-row chunk, 16B slot lane&7, XOR-swizzled k source
  const int sr = lane >> 3, sc = lane & 7;
  const int kch = (sc ^ sr) * 8;
  const unsigned short* Ag[4]; unsigned short* Al[4];
#pragma unroll
  for (int j = 0; j < 4; j++) {
    int c = wave * 4 + j;
    Ag[j] = A + (size_t)(m0 + c * 8 + sr) * lda + kch;
    Al[j] = As + c * 512;
  }
  const unsigned short* Bg[BC]; unsigned short* Bl[BC];
#pragma unroll
  for (int j = 0; j < BC; j++) {
    int c = wave * BC + j;
    Bg[j] = Bt + (size_t)(n0 + c * 8 + sr) * ldb + kch;
    Bl[j] = Bs + c * 512;
  }

  float16v acc[2][NTW];
#pragma unroll
  for (int i = 0; i < 2; i++)
#pragma unroll
    for (int j = 0; j < NTW; j++)
#pragma unroll
      for (int r = 0; r < 16; r++) acc[i][j][r] = 0.f;

  const int rt = lane & 31;   // row (A) / col (B) within a 32-tile
  const int h  = lane >> 5;   // k-half: k = 8*h + j
  const int s7 = lane & 7;

  for (int k0 = 0; k0 < K; k0 += 64) {
    if (k0) __syncthreads();
#pragma unroll
    for (int j = 0; j < 4; j++) gld_lds16(Ag[j] + k0, Al[j]);
#pragma unroll
    for (int j = 0; j < BC; j++) gld_lds16(Bg[j] + k0, Bl[j]);
    __syncthreads();
#pragma unroll
    for (int kt = 0; kt < 4; kt++) {
      const int sl = ((kt * 2 + h) ^ s7) * 8;
      short8 af[2], bfr[NTW];
#pragma unroll
      for (int mt = 0; mt < 2; mt++)
        af[mt] = *(const short8*)(As + (mq + mt * 32 + rt) * 64 + sl);
#pragma unroll
      for (int nt = 0; nt < NTW; nt++)
        bfr[nt] = *(const short8*)(Bs + (nq + nt * 32 + rt) * 64 + sl);
#pragma unroll
      for (int mt = 0; mt < 2; mt++)
#pragma unroll
        for (int nt = 0; nt < NTW; nt++)
          acc[mt][nt] = __builtin_amdgcn_mfma_f32_32x32x16_bf16(af[mt], bfr[nt], acc[mt][nt], 0, 0, 0);
    }
  }

  // C/D layout: col = rt, row = (reg&3) + 8*(reg>>2) + 4*h
  if (mode == 1) {
    unsigned short* Cb = (unsigned short*)Cv + (size_t)z * scz;
    float* ls = lsum + (size_t)z * slz;
#pragma unroll
    for (int mt = 0; mt < 2; mt++) {
      float rs[16];
#pragma unroll
      for (int r = 0; r < 16; r++) rs[r] = 0.f;
#pragma unroll
      for (int r = 0; r < 16; r++) {
        int gm = m0 + mq + mt * 32 + (r & 3) + 8 * (r >> 2) + 4 * h;
#pragma unroll
        for (int nt = 0; nt < NTW; nt++) {
          float e = __expf(acc[mt][nt][r] * scale);
          Cb[(size_t)gm * ldc + n0 + nq + nt * 32 + rt] = f2bf(e);
          rs[r] += e;
        }
      }
#pragma unroll
      for (int r = 0; r < 16; r++) {
        float s = rs[r];
#pragma unroll
        for (int o = 1; o < 32; o <<= 1) s += __shfl_xor(s, o);
        rs[r] = s;
      }
      if (rt == 0)
#pragma unroll
        for (int r = 0; r < 16; r++)
          atomicAdd(&ls[m0 + mq + mt * 32 + (r & 3) + 8 * (r >> 2) + 4 * h], rs[r]);
    }
  } else if (mode == 2) {
    unsigned short* Cb = (unsigned short*)Cv + (size_t)z * scz;
    const float* ls = lsum + (size_t)z * slz;
#pragma unroll
    for (int mt = 0; mt < 2; mt++)
#pragma unroll
      for (int r = 0; r < 16; r++) {
        int gm = m0 + mq + mt * 32 + (r & 3) + 8 * (r >> 2) + 4 * h;
        float li = 1.f / ls[gm];
#pragma unroll
        for (int nt = 0; nt < NTW; nt++)
          Cb[(size_t)gm * ldc + n0 + nq + nt * 32 + rt] = f2bf(acc[mt][nt][r] * li);
      }
  } else {
    float* Cf = (float*)Cv + (size_t)z * scz;
    unsigned short* Cb = (unsigned short*)Cv + (size_t)z * scz;
    float bv[NTW];
#pragma unroll
    for (int nt = 0; nt < NTW; nt++) bv[nt] = bias[n0 + nq + nt * 32 + rt];
#pragma unroll
    for (int mt = 0; mt < 2; mt++)
#pragma unroll
      for (int r = 0; r < 16; r++) {
        int gm = m0 + mq + mt * 32 + (r & 3) + 8 * (r >> 2) + 4 * h;
#pragma unroll
        for (int nt = 0; nt < NTW; nt++) {
          float v = acc[mt][nt][r] + bv[nt];
          if (mode == 0) Cf[(size_t)gm * ldc + n0 + nq + nt * 32 + rt] = v;
          else           Cb[(size_t)gm * ldc + n0 + nq + nt * 32 + rt] = f2bf(v);
        }
      }
  }
}

extern "C" void kernel_launch(void* const* d_in, const int* in_sizes, int n_in,
                              void* d_out, int out_size, void* d_ws, size_t ws_size,
                              hipStream_t stream) {
  const float* x   = (const float*)d_in[0];
  const float* Wq  = (const float*)d_in[1];
  const float* bq  = (const float*)d_in[2];
  const float* Wk  = (const float*)d_in[3];
  const float* bk  = (const float*)d_in[4];
  const float* Wov = (const float*)d_in[5];
  const float* bov = (const float*)d_in[6];
  float* out = (float*)d_out;

  char* ws = (char*)d_ws;
  size_t off = 0;
  auto alloc = [&](size_t bytes) {
    char* p = ws + off;
    off += (bytes + 255) & ~(size_t)255;
    return p;
  };
  const int M = BATCH * SEQ;  // 16384
  unsigned short* x_bf = (unsigned short*)alloc((size_t)M * EMB * 2);
  unsigned short* xT   = (unsigned short*)alloc((size_t)M * EMB * 2);
  unsigned short* WqkT = (unsigned short*)alloc((size_t)2 * PDIM * EMB * 2);
  unsigned short* WovT = (unsigned short*)alloc((size_t)EMB * EMB * 2);
  float*          bqk  = (float*)alloc(2 * PDIM * sizeof(float));
  unsigned short* qk   = (unsigned short*)alloc((size_t)M * 2 * PDIM * 2);
  float*          linv = (float*)alloc((size_t)M * sizeof(float));
  unsigned short* ctx  = (unsigned short*)alloc((size_t)M * EMB * 2);
  const size_t pslot = (size_t)SEQ * SEQ * 2;
  unsigned short* P = (unsigned short*)(ws + off);
  size_t rem = ws_size > off ? ws_size - off : 0;
  int g = (rem >= 4 * pslot) ? 4 : (rem >= 2 * pslot) ? 2 : 1;

  // ---- prep (2 launches) ----
  xprep_kernel<<<dim3(EMB / 64, SEQ / 64, BATCH), 256, 0, stream>>>(x, x_bf, xT);
  wprep_kernel<<<dim3(1345), 256, 0, stream>>>(Wq, Wk, Wov, WqkT, WovT, bq, bk, bqk, linv);

  // ---- qk projection: (16384 x 1024) @ (256 x 1024)^T + bqk -> bf16 ----
  gemm_kernel<128><<<dim3(M / 128, 2, 1), 256, 0, stream>>>(
      x_bf, EMB, 0, WqkT, EMB, 0, qk, 2 * PDIM, 0, EMB, bqk, nullptr, 0, 1.f, 3);

  const float qscale = 0.08838834764831845f;  // 1/sqrt(128)
  for (int b0 = 0; b0 < BATCH; b0 += g) {
    int gg = (b0 + g <= BATCH) ? g : (BATCH - b0);
    // S-GEMM: P~ = exp(scale * q @ k^T) + fused atomic rowsum
    gemm_kernel<256><<<dim3(SEQ / 128, SEQ / 256, gg), 256, 0, stream>>>(
        qk + (size_t)b0 * SEQ * 2 * PDIM, 2 * PDIM, (size_t)SEQ * 2 * PDIM,
        qk + (size_t)b0 * SEQ * 2 * PDIM + PDIM, 2 * PDIM, (size_t)SEQ * 2 * PDIM,
        P, SEQ, (size_t)SEQ * SEQ,
        PDIM, nullptr, linv + (size_t)b0 * SEQ, SEQ, qscale, 1);
    // PV: ctx = (P~ @ xT^T) / l
    gemm_kernel<256><<<dim3(SEQ / 128, EMB / 256, gg), 256, 0, stream>>>(
        P, SEQ, (size_t)SEQ * SEQ,
        xT + (size_t)b0 * EMB * SEQ, SEQ, (size_t)EMB * SEQ,
        ctx + (size_t)b0 * SEQ * EMB, EMB, (size_t)SEQ * EMB,
        SEQ, nullptr, linv + (size_t)b0 * SEQ, SEQ, 1.f, 2);
  }

  // ---- out projection: out = ctx @ WovT^T + bov (fp32) ----
  gemm_kernel<256><<<dim3(M / 128, EMB / 256, 1), 256, 0, stream>>>(
      ctx, EMB, 0, WovT, EMB, 0, out, EMB, 0, EMB, bov, nullptr, 0, 1.f, 0);
}